// Round 5
// baseline (242.294 us; speedup 1.0000x reference)
//
#include <hip/hip_runtime.h>
#include <math.h>

#define BB 64
#define II 1024
#define HH 1024

typedef float f4 __attribute__((ext_vector_type(4)));

// ws layout (floats)
#define WS_I     0
#define WS_F     64
#define WS_INVN  128
#define WS_DENOM 192
#define WS_O     256
#define WS_K     (256 + 65536)
#define WS_V     (256 + 2*65536)
#define WS_Q     (256 + 3*65536)

// ---------------- kernel 1: per-batch gates + input norm ----------------
__global__ __launch_bounds__(64) void k_gates(const float* __restrict__ input,
                                              const float* __restrict__ if_w,
                                              const float* __restrict__ if_b,
                                              float* __restrict__ ws) {
    int b = blockIdx.x;
    int lane = threadIdx.x;
    const float4* x4 = (const float4*)(input + (size_t)b * II);
    const float4* w0 = (const float4*)(if_w);
    const float4* w1 = (const float4*)(if_w + II);
    float d0 = 0.f, d1 = 0.f, ss = 0.f;
#pragma unroll
    for (int j = 0; j < 4; ++j) {
        int idx = lane + j * 64;
        float4 xv = x4[idx];
        float4 a = w0[idx];
        float4 c = w1[idx];
        d0 += xv.x*a.x + xv.y*a.y + xv.z*a.z + xv.w*a.w;
        d1 += xv.x*c.x + xv.y*c.y + xv.z*c.z + xv.w*c.w;
        ss += xv.x*xv.x + xv.y*xv.y + xv.z*xv.z + xv.w*xv.w;
    }
#pragma unroll
    for (int off = 32; off > 0; off >>= 1) {
        d0 += __shfl_xor(d0, off);
        d1 += __shfl_xor(d1, off);
        ss += __shfl_xor(ss, off);
    }
    if (lane == 0) {
        ws[WS_I + b]    = expf(d0 + if_b[0]);
        ws[WS_F + b]    = expf(d1 + if_b[1]);
        ws[WS_INVN + b] = 1.0f / sqrtf(ss);
    }
}

// ---------------- kernel 2: blocked o/k/v/q projections (+ n update) ----------------
// (byte-identical to R3 for clean attribution)
__global__ __launch_bounds__(512) void k_proj(const float* __restrict__ input,
                                              const float* __restrict__ o_w,
                                              const float* __restrict__ kvq_w,
                                              const float* __restrict__ o_b,
                                              const float* __restrict__ kvq_b,
                                              const float* __restrict__ prev_n,
                                              float* __restrict__ ws,
                                              float* __restrict__ n_out) {
    __shared__ float xl[64 * 512];          // 128 KB
    float4* xl4 = (float4*)xl;
    const float4* in4 = (const float4*)input;

    int t = threadIdx.x;
    int wave = t >> 6, lane = t & 63;
    int gr0 = blockIdx.x * 16 + wave * 2;
    const float* wb0 = (gr0 < HH) ? (o_w + (size_t)gr0 * II)
                                  : (kvq_w + (size_t)(gr0 - HH) * II);
    const float* wb1 = wb0 + II;

    float acc0 = 0.f, acc1 = 0.f;
    int sw = lane & 7;

    for (int h = 0; h < 2; ++h) {
        if (h) __syncthreads();
#pragma unroll
        for (int j = 0; j < 16; ++j) {
            int e4 = t + j * 512;
            int b  = e4 >> 7;
            int kq = e4 & 127;
            float4 v = in4[b * 256 + h * 128 + kq];
            xl4[b * 128 + (kq ^ (b & 7))] = v;
        }
        __syncthreads();

        const float4* w40 = (const float4*)(wb0 + h * 512);
        const float4* w41 = (const float4*)(wb1 + h * 512);
        const float4* xb  = xl4 + lane * 128;
#pragma unroll 8
        for (int q = 0; q < 128; ++q) {
            float4 xv = xb[q ^ sw];
            float4 w0 = w40[q];
            float4 w1 = w41[q];
            acc0 += w0.x*xv.x + w0.y*xv.y + w0.z*xv.z + w0.w*xv.w;
            acc1 += w1.x*xv.x + w1.y*xv.y + w1.z*xv.z + w1.w*xv.w;
        }
    }

    float invn = ws[WS_INVN + lane];
    float fb   = ws[WS_F + lane];
    float ib   = ws[WS_I + lane];
#pragma unroll
    for (int r = 0; r < 2; ++r) {
        int gr = gr0 + r;
        float d = r ? acc1 : acc0;
        if (gr < HH) {
            ws[WS_O + lane * HH + gr] = 1.0f / (1.0f + expf(-(d + o_b[gr])));
        } else {
            int wk = gr - HH;
            int which = wk >> 10;
            int hh = wk & 1023;
            float dn = d * invn;
            if (which == 0) {
                float kv = dn * 0.03125f + kvq_b[hh];
                ws[WS_K + lane * HH + hh] = kv;
                n_out[lane * HH + hh] = fb * prev_n[lane * HH + hh] + ib * kv;
            } else if (which == 1) {
                ws[WS_V + lane * HH + hh] = dn + kvq_b[HH + hh];
            } else {
                ws[WS_Q + lane * HH + hh] = dn + kvq_b[2 * HH + hh];
            }
        }
    }
}

// ---------------- kernel 3: denom = max(|n.q|, 1) per batch ----------------
__global__ __launch_bounds__(256) void k_denom(const float* __restrict__ n_out,
                                               float* __restrict__ ws) {
    int b = blockIdx.x;
    int t = threadIdx.x;
    int wave = t >> 6, lane = t & 63;
    const float* nb = n_out + (size_t)b * HH;
    const float* qb = ws + WS_Q + (size_t)b * HH;
    float s = 0.f;
    for (int idx = t; idx < HH; idx += 256) s += nb[idx] * qb[idx];
#pragma unroll
    for (int off = 32; off > 0; off >>= 1) s += __shfl_xor(s, off);
    __shared__ float red[4];
    if (lane == 0) red[wave] = s;
    __syncthreads();
    if (t == 0) {
        float tot = red[0] + red[1] + red[2] + red[3];
        ws[WS_DENOM + b] = fmaxf(fabsf(tot), 1.0f);
    }
}

// ---------------- kernel 4: c update + fused readout h (R3 register version) ----------------
__global__ __launch_bounds__(256) void k_cup(const float* __restrict__ prev_c,
                                             const float* __restrict__ ws,
                                             float* __restrict__ c_out,
                                             float* __restrict__ h_out) {
    int wave = threadIdx.x >> 6, lane = threadIdx.x & 63;
    int g0 = (blockIdx.x * 4 + wave) * 4;    // first of 4 rows, all same batch
    int b = g0 >> 10;
    float fb = ws[WS_F + b], ib = ws[WS_I + b];
    float iv0 = ib * ws[WS_V + g0];
    float iv1 = ib * ws[WS_V + g0 + 1];
    float iv2 = ib * ws[WS_V + g0 + 2];
    float iv3 = ib * ws[WS_V + g0 + 3];
    const f4* pc = (const f4*)(prev_c + ((size_t)g0 << 10));
    f4*       co = (f4*)(c_out + ((size_t)g0 << 10));
    const float4* k4 = (const float4*)(ws + WS_K + (size_t)b * HH);
    const float4* q4 = (const float4*)(ws + WS_Q + (size_t)b * HH);
    float s0 = 0.f, s1 = 0.f, s2 = 0.f, s3 = 0.f;
#pragma unroll
    for (int j = 0; j < 4; ++j) {
        int idx = lane + j * 64;
        float4 kv = k4[idx], qv = q4[idx];
        f4 p, c;
        p = __builtin_nontemporal_load(&pc[idx]);
        c.x = fb*p.x + iv0*kv.x; c.y = fb*p.y + iv0*kv.y;
        c.z = fb*p.z + iv0*kv.z; c.w = fb*p.w + iv0*kv.w;
        __builtin_nontemporal_store(c, &co[idx]);
        s0 += c.x*qv.x + c.y*qv.y + c.z*qv.z + c.w*qv.w;

        p = __builtin_nontemporal_load(&pc[idx + 256]);
        c.x = fb*p.x + iv1*kv.x; c.y = fb*p.y + iv1*kv.y;
        c.z = fb*p.z + iv1*kv.z; c.w = fb*p.w + iv1*kv.w;
        __builtin_nontemporal_store(c, &co[idx + 256]);
        s1 += c.x*qv.x + c.y*qv.y + c.z*qv.z + c.w*qv.w;

        p = __builtin_nontemporal_load(&pc[idx + 512]);
        c.x = fb*p.x + iv2*kv.x; c.y = fb*p.y + iv2*kv.y;
        c.z = fb*p.z + iv2*kv.z; c.w = fb*p.w + iv2*kv.w;
        __builtin_nontemporal_store(c, &co[idx + 512]);
        s2 += c.x*qv.x + c.y*qv.y + c.z*qv.z + c.w*qv.w;

        p = __builtin_nontemporal_load(&pc[idx + 768]);
        c.x = fb*p.x + iv3*kv.x; c.y = fb*p.y + iv3*kv.y;
        c.z = fb*p.z + iv3*kv.z; c.w = fb*p.w + iv3*kv.w;
        __builtin_nontemporal_store(c, &co[idx + 768]);
        s3 += c.x*qv.x + c.y*qv.y + c.z*qv.z + c.w*qv.w;
    }
#pragma unroll
    for (int off = 32; off > 0; off >>= 1) {
        s0 += __shfl_xor(s0, off);
        s1 += __shfl_xor(s1, off);
        s2 += __shfl_xor(s2, off);
        s3 += __shfl_xor(s3, off);
    }
    if (lane == 0) {
        float inv_d = 1.0f / ws[WS_DENOM + b];
        h_out[g0]     = ws[WS_O + g0]     * s0 * inv_d;
        h_out[g0 + 1] = ws[WS_O + g0 + 1] * s1 * inv_d;
        h_out[g0 + 2] = ws[WS_O + g0 + 2] * s2 * inv_d;
        h_out[g0 + 3] = ws[WS_O + g0 + 3] * s3 * inv_d;
    }
}

extern "C" void kernel_launch(void* const* d_in, const int* in_sizes, int n_in,
                              void* d_out, int out_size, void* d_ws, size_t ws_size,
                              hipStream_t stream) {
    const float* input  = (const float*)d_in[0];
    const float* prev_c = (const float*)d_in[2];
    const float* prev_n = (const float*)d_in[3];
    const float* if_w   = (const float*)d_in[4];
    const float* o_w    = (const float*)d_in[5];
    const float* kvq_w  = (const float*)d_in[6];
    const float* if_b   = (const float*)d_in[7];
    const float* o_b    = (const float*)d_in[8];
    const float* kvq_b  = (const float*)d_in[9];

    float* out   = (float*)d_out;
    float* h_out = out;                          // [B,H]
    float* c_out = out + 65536;                  // [B,H,H]
    float* n_out = out + 65536 + 67108864;       // [B,H]
    float* ws    = (float*)d_ws;

    k_gates<<<BB, 64, 0, stream>>>(input, if_w, if_b, ws);
    k_proj <<<256, 512, 0, stream>>>(input, o_w, kvq_w, o_b, kvq_b, prev_n, ws, n_out);
    k_denom<<<BB, 256, 0, stream>>>(n_out, ws);
    // IDENTIFICATION: k_cup launched TWICE (idempotent, deterministic).
    // k_cup_dur = T - 147 (R3 total); proj+small = 294 - T.
    k_cup  <<<4096, 256, 0, stream>>>(prev_c, ws, c_out, h_out);
    k_cup  <<<4096, 256, 0, stream>>>(prev_c, ws, c_out, h_out);
}

// Round 6
// 150.935 us; speedup vs baseline: 1.6053x; 1.6053x over previous
//
#include <hip/hip_runtime.h>
#include <math.h>

#define BB 64
#define II 1024
#define HH 1024

typedef float f4 __attribute__((ext_vector_type(4)));

// ws layout (floats)
#define WS_I     0
#define WS_F     64
#define WS_INVN  128
#define WS_DENOM 192
#define WS_O     256
#define WS_K     (256 + 65536)
#define WS_V     (256 + 2*65536)
#define WS_Q     (256 + 3*65536)

// ---------------- kernel 1: per-batch gates + input norm ----------------
__global__ __launch_bounds__(64) void k_gates(const float* __restrict__ input,
                                              const float* __restrict__ if_w,
                                              const float* __restrict__ if_b,
                                              float* __restrict__ ws) {
    int b = blockIdx.x;
    int lane = threadIdx.x;
    const float4* x4 = (const float4*)(input + (size_t)b * II);
    const float4* w0 = (const float4*)(if_w);
    const float4* w1 = (const float4*)(if_w + II);
    float d0 = 0.f, d1 = 0.f, ss = 0.f;
#pragma unroll
    for (int j = 0; j < 4; ++j) {
        int idx = lane + j * 64;
        float4 xv = x4[idx];
        float4 a = w0[idx];
        float4 c = w1[idx];
        d0 += xv.x*a.x + xv.y*a.y + xv.z*a.z + xv.w*a.w;
        d1 += xv.x*c.x + xv.y*c.y + xv.z*c.z + xv.w*c.w;
        ss += xv.x*xv.x + xv.y*xv.y + xv.z*xv.z + xv.w*xv.w;
    }
#pragma unroll
    for (int off = 32; off > 0; off >>= 1) {
        d0 += __shfl_xor(d0, off);
        d1 += __shfl_xor(d1, off);
        ss += __shfl_xor(ss, off);
    }
    if (lane == 0) {
        ws[WS_I + b]    = expf(d0 + if_b[0]);
        ws[WS_F + b]    = expf(d1 + if_b[1]);
        ws[WS_INVN + b] = 1.0f / sqrtf(ss);
    }
}

// ---------------- kernel 2: register-held o/k/v/q projections (+ n update) ----------------
// No big-LDS staging, no conflicted ds_read. 8 waves; wave w owns k-slice
// [128w, 128w+128); lane = batch holds X[lane][slice] in 32 f4 regs (L2-served,
// loaded once per block). Per row: 32 wave-uniform 16B weight loads (weights
// read exactly once from HBM across the grid) + 128 FMAs -> partial in
// pl[row][wave][lane] (32 KB LDS, stride-1 lanes = conflict-free). One barrier,
// 8-way reduce, same epilogue as before. grid = 256 blocks x 512 threads.
__global__ __launch_bounds__(512, 2) void k_proj(const float* __restrict__ input,
                                                 const float* __restrict__ o_w,
                                                 const float* __restrict__ kvq_w,
                                                 const float* __restrict__ o_b,
                                                 const float* __restrict__ kvq_b,
                                                 const float* __restrict__ prev_n,
                                                 float* __restrict__ ws,
                                                 float* __restrict__ n_out) {
    __shared__ float pl[16 * 512];          // [row][wave][batch], 32 KB

    int t = threadIdx.x;
    int w = t >> 6, lane = t & 63;          // lane = batch
    int rbase = blockIdx.x * 16;

    // stage this lane's X k-slice into registers (uncoalesced but L2-resident,
    // once per block; reused by all 16 rows)
    const f4* xs = (const f4*)(input + (size_t)lane * II + w * 128);
    f4 xr[32];
#pragma unroll
    for (int q = 0; q < 32; ++q) xr[q] = xs[q];

    // 16 rows: partial dot over this wave's k-slice
    for (int r = 0; r < 16; ++r) {
        int gr = rbase + r;
        const float* wrow = (gr < HH) ? (o_w + (size_t)gr * II)
                                      : (kvq_w + (size_t)(gr - HH) * II);
        const f4* w4 = (const f4*)(wrow + w * 128);
        float acc = 0.f;
#pragma unroll
        for (int q = 0; q < 32; ++q) {
            f4 wv = w4[q];
            acc += wv.x*xr[q].x + wv.y*xr[q].y + wv.z*xr[q].z + wv.w*xr[q].w;
        }
        pl[r * 512 + w * 64 + lane] = acc;
    }
    __syncthreads();

    // reduce 8 wave-partials + epilogue; thread (w, lane) handles rows 2w, 2w+1
    float invn = ws[WS_INVN + lane];
    float fb   = ws[WS_F + lane];
    float ib   = ws[WS_I + lane];
#pragma unroll
    for (int rr = 0; rr < 2; ++rr) {
        int r  = 2 * w + rr;
        int gr = rbase + r;
        float d = 0.f;
#pragma unroll
        for (int j = 0; j < 8; ++j) d += pl[r * 512 + j * 64 + lane];
        if (gr < HH) {
            ws[WS_O + lane * HH + gr] = 1.0f / (1.0f + expf(-(d + o_b[gr])));
        } else {
            int wk = gr - HH;
            int which = wk >> 10;
            int hh = wk & 1023;
            float dn = d * invn;
            if (which == 0) {
                float kv = dn * 0.03125f + kvq_b[hh];      // 1/sqrt(1024)
                ws[WS_K + lane * HH + hh] = kv;
                n_out[lane * HH + hh] = fb * prev_n[lane * HH + hh] + ib * kv;
            } else if (which == 1) {
                ws[WS_V + lane * HH + hh] = dn + kvq_b[HH + hh];
            } else {
                ws[WS_Q + lane * HH + hh] = dn + kvq_b[2 * HH + hh];
            }
        }
    }
}

// ---------------- kernel 3: denom = max(|n.q|, 1) per batch ----------------
__global__ __launch_bounds__(256) void k_denom(const float* __restrict__ n_out,
                                               float* __restrict__ ws) {
    int b = blockIdx.x;
    int t = threadIdx.x;
    int wave = t >> 6, lane = t & 63;
    const float* nb = n_out + (size_t)b * HH;
    const float* qb = ws + WS_Q + (size_t)b * HH;
    float s = 0.f;
    for (int idx = t; idx < HH; idx += 256) s += nb[idx] * qb[idx];
#pragma unroll
    for (int off = 32; off > 0; off >>= 1) s += __shfl_xor(s, off);
    __shared__ float red[4];
    if (lane == 0) red[wave] = s;
    __syncthreads();
    if (t == 0) {
        float tot = red[0] + red[1] + red[2] + red[3];
        ws[WS_DENOM + b] = fmaxf(fabsf(tot), 1.0f);
    }
}

// ---------------- kernel 4: c update + fused readout h (R3 register version) ----------------
__global__ __launch_bounds__(256) void k_cup(const float* __restrict__ prev_c,
                                             const float* __restrict__ ws,
                                             float* __restrict__ c_out,
                                             float* __restrict__ h_out) {
    int wave = threadIdx.x >> 6, lane = threadIdx.x & 63;
    int g0 = (blockIdx.x * 4 + wave) * 4;    // first of 4 rows, all same batch
    int b = g0 >> 10;
    float fb = ws[WS_F + b], ib = ws[WS_I + b];
    float iv0 = ib * ws[WS_V + g0];
    float iv1 = ib * ws[WS_V + g0 + 1];
    float iv2 = ib * ws[WS_V + g0 + 2];
    float iv3 = ib * ws[WS_V + g0 + 3];
    const f4* pc = (const f4*)(prev_c + ((size_t)g0 << 10));
    f4*       co = (f4*)(c_out + ((size_t)g0 << 10));
    const float4* k4 = (const float4*)(ws + WS_K + (size_t)b * HH);
    const float4* q4 = (const float4*)(ws + WS_Q + (size_t)b * HH);
    float s0 = 0.f, s1 = 0.f, s2 = 0.f, s3 = 0.f;
#pragma unroll
    for (int j = 0; j < 4; ++j) {
        int idx = lane + j * 64;
        float4 kv = k4[idx], qv = q4[idx];
        f4 p, c;
        p = __builtin_nontemporal_load(&pc[idx]);
        c.x = fb*p.x + iv0*kv.x; c.y = fb*p.y + iv0*kv.y;
        c.z = fb*p.z + iv0*kv.z; c.w = fb*p.w + iv0*kv.w;
        __builtin_nontemporal_store(c, &co[idx]);
        s0 += c.x*qv.x + c.y*qv.y + c.z*qv.z + c.w*qv.w;

        p = __builtin_nontemporal_load(&pc[idx + 256]);
        c.x = fb*p.x + iv1*kv.x; c.y = fb*p.y + iv1*kv.y;
        c.z = fb*p.z + iv1*kv.z; c.w = fb*p.w + iv1*kv.w;
        __builtin_nontemporal_store(c, &co[idx + 256]);
        s1 += c.x*qv.x + c.y*qv.y + c.z*qv.z + c.w*qv.w;

        p = __builtin_nontemporal_load(&pc[idx + 512]);
        c.x = fb*p.x + iv2*kv.x; c.y = fb*p.y + iv2*kv.y;
        c.z = fb*p.z + iv2*kv.z; c.w = fb*p.w + iv2*kv.w;
        __builtin_nontemporal_store(c, &co[idx + 512]);
        s2 += c.x*qv.x + c.y*qv.y + c.z*qv.z + c.w*qv.w;

        p = __builtin_nontemporal_load(&pc[idx + 768]);
        c.x = fb*p.x + iv3*kv.x; c.y = fb*p.y + iv3*kv.y;
        c.z = fb*p.z + iv3*kv.z; c.w = fb*p.w + iv3*kv.w;
        __builtin_nontemporal_store(c, &co[idx + 768]);
        s3 += c.x*qv.x + c.y*qv.y + c.z*qv.z + c.w*qv.w;
    }
#pragma unroll
    for (int off = 32; off > 0; off >>= 1) {
        s0 += __shfl_xor(s0, off);
        s1 += __shfl_xor(s1, off);
        s2 += __shfl_xor(s2, off);
        s3 += __shfl_xor(s3, off);
    }
    if (lane == 0) {
        float inv_d = 1.0f / ws[WS_DENOM + b];
        h_out[g0]     = ws[WS_O + g0]     * s0 * inv_d;
        h_out[g0 + 1] = ws[WS_O + g0 + 1] * s1 * inv_d;
        h_out[g0 + 2] = ws[WS_O + g0 + 2] * s2 * inv_d;
        h_out[g0 + 3] = ws[WS_O + g0 + 3] * s3 * inv_d;
    }
}

extern "C" void kernel_launch(void* const* d_in, const int* in_sizes, int n_in,
                              void* d_out, int out_size, void* d_ws, size_t ws_size,
                              hipStream_t stream) {
    const float* input  = (const float*)d_in[0];
    const float* prev_c = (const float*)d_in[2];
    const float* prev_n = (const float*)d_in[3];
    const float* if_w   = (const float*)d_in[4];
    const float* o_w    = (const float*)d_in[5];
    const float* kvq_w  = (const float*)d_in[6];
    const float* if_b   = (const float*)d_in[7];
    const float* o_b    = (const float*)d_in[8];
    const float* kvq_b  = (const float*)d_in[9];

    float* out   = (float*)d_out;
    float* h_out = out;                          // [B,H]
    float* c_out = out + 65536;                  // [B,H,H]
    float* n_out = out + 65536 + 67108864;       // [B,H]
    float* ws    = (float*)d_ws;

    k_gates<<<BB, 64, 0, stream>>>(input, if_w, if_b, ws);
    k_proj <<<256, 512, 0, stream>>>(input, o_w, kvq_w, o_b, kvq_b, prev_n, ws, n_out);
    k_denom<<<BB, 256, 0, stream>>>(n_out, ws);
    k_cup  <<<4096, 256, 0, stream>>>(prev_c, ws, c_out, h_out);
}